// Round 10
// baseline (187.928 us; speedup 1.0000x reference)
//
#include <hip/hip_runtime.h>

typedef unsigned short u16;
typedef unsigned int u32;
using frag16 = __attribute__((ext_vector_type(8))) short;   // 8 x bf16 (4 VGPRs)
using facc   = __attribute__((ext_vector_type(4))) float;   // 4 x fp32 acc
using facc16 = __attribute__((ext_vector_type(16))) float;  // 16 x fp32 acc

#define DEV static __device__ __forceinline__

DEV u16 f2bf(float f) {
  union { float f; unsigned u; } v; v.f = f;
  unsigned r = v.u + 0x7fffu + ((v.u >> 16) & 1u);
  return (u16)(r >> 16);
}
DEV unsigned fbits(float f) {
  union { float f; unsigned u; } v; v.f = f;
  return v.u;
}
// pack two fp32 -> two bf16 (lo in low half), round-half-up
DEV unsigned pkbf(float lo, float hi) {
  return __builtin_amdgcn_perm(fbits(hi) + 0x8000u, fbits(lo) + 0x8000u, 0x07060302u);
}
// async global->LDS, 16B per lane. LDS dest = wave-uniform base + lane*16.
DEV void gld16(const u16* g, u16* l) {
  __builtin_amdgcn_global_load_lds(
      (__attribute__((address_space(1))) unsigned int*)(g),
      (__attribute__((address_space(3))) unsigned int*)(l), 16, 0, 0);
}

// ---------------- K1: x cvt (0..4095) + weight transposes (..6399) + gate ----
__global__ __launch_bounds__(256) void prep_gate_kernel(const float4* __restrict__ x,
    const float* __restrict__ Wq, const float* __restrict__ Wk,
    const float* __restrict__ Wv, const float* __restrict__ Wo,
    const float* __restrict__ ctx, const float* __restrict__ W1,
    const float* __restrict__ b1, const float* __restrict__ W2,
    const float* __restrict__ b2,
    u16* __restrict__ xb, u16* __restrict__ WqT, u16* __restrict__ WkT,
    u16* __restrict__ WvT, u16* __restrict__ WoT, u16* __restrict__ gctx) {
  int bid = blockIdx.x;
  if (bid < 4096) {
    int id = bid * 256 + threadIdx.x;
    float4 v = x[id];
    ushort4 o;
    o.x = f2bf(v.x); o.y = f2bf(v.y); o.z = f2bf(v.z); o.w = f2bf(v.w);
    *(ushort4*)(xb + (size_t)id * 4) = o;
  } else if (bid < 6400) {
    int id = (bid - 4096) * 256 + threadIdx.x;   // 589824 total
    const float* W; u16* WT; int K, idx;
    if (id < 262144)      { W = Wq; WT = WqT; K = 512; idx = id; }
    else if (id < 294912) { W = Wk; WT = WkT; K = 64;  idx = id - 262144; }
    else if (id < 327680) { W = Wv; WT = WvT; K = 64;  idx = id - 294912; }
    else                  { W = Wo; WT = WoT; K = 512; idx = id - 327680; }
    int n = idx / K, k = idx - n * K;
    WT[idx] = f2bf(W[k * 512 + n]);
  } else {
    // gate: gctx = bf16(ctx * sigmoid(relu(ctx@W1+b1)@W2+b2))
    int wave = threadIdx.x >> 6, lane = threadIdx.x & 63;
    int row = (bid - 6400) * 4 + wave;          // 8192 rows
    __shared__ float sc[4][64];
    float cv = ctx[(size_t)row * 64 + lane];
    sc[wave][lane] = cv;
    __syncthreads();
    float h = 0.f;
    if (lane < 32) {
      h = b1[lane];
      #pragma unroll
      for (int i = 0; i < 64; ++i) h += sc[wave][i] * W1[i * 32 + lane];
      h = fmaxf(h, 0.f) * W2[lane];
    }
    #pragma unroll
    for (int off = 32; off; off >>= 1) h += __shfl_xor(h, off);
    float g = 1.f / (1.f + __expf(-(h + b2[0])));
    gctx[(size_t)row * 64 + lane] = f2bf(cv * g);
  }
}

// ---------------- big GEMM body: 128x64 tile, BK=64, gld16 --------------------
// MODE 0: bf16 out * scale. MODE 2: fp32 out + bias.
template<int MODE>
DEV void gemm128_body(const u16* __restrict__ A, const u16* __restrict__ BT,
                      void* __restrict__ Cp, const float* __restrict__ bias,
                      int m0, int n0, float scale,
                      u16* As0, u16* As1, u16* Bs0, u16* Bs1) {
  const int K = 512, N = 512;
  const int lane = threadIdx.x & 63, wave = threadIdx.x >> 6;
  const int quad = lane >> 4, l16 = lane & 15;
  const int wr = wave >> 1, wc = wave & 1;

  const u16* gA = A + (size_t)(m0 + wave * 32 + (lane >> 2)) * K + (lane & 3) * 8;
  const u16* gB = BT + (size_t)(n0 + wave * 16 + (lane >> 2)) * K + (lane & 3) * 8;

  facc acc[4][2] = {};

  for (int k0 = 0; k0 < K; k0 += 64) {
    if (k0) __syncthreads();
    gld16(gA + k0,           As0 + wave * 1024);
    gld16(gA + 16 * K + k0,  As0 + wave * 1024 + 512);
    gld16(gA + k0 + 32,          As1 + wave * 1024);
    gld16(gA + 16 * K + k0 + 32, As1 + wave * 1024 + 512);
    gld16(gB + k0,      Bs0 + wave * 512);
    gld16(gB + k0 + 32, Bs1 + wave * 512);
    __syncthreads();

    #pragma unroll
    for (int hh = 0; hh < 2; ++hh) {
      const u16* Ah = hh ? As1 : As0;
      const u16* Bh = hh ? Bs1 : Bs0;
      frag16 af[4], bf[2];
      #pragma unroll
      for (int rt = 0; rt < 4; ++rt)
        af[rt] = *(const frag16*)(Ah + (wr * 64 + rt * 16 + l16) * 32 + quad * 8);
      #pragma unroll
      for (int ct = 0; ct < 2; ++ct)
        bf[ct] = *(const frag16*)(Bh + (wc * 32 + ct * 16 + l16) * 32 + quad * 8);
      #pragma unroll
      for (int rt = 0; rt < 4; ++rt)
        #pragma unroll
        for (int ct = 0; ct < 2; ++ct)
          acc[rt][ct] = __builtin_amdgcn_mfma_f32_16x16x32_bf16(af[rt], bf[ct], acc[rt][ct], 0, 0, 0);
    }
  }

  #pragma unroll
  for (int rt = 0; rt < 4; ++rt) {
    #pragma unroll
    for (int ct = 0; ct < 2; ++ct) {
      int col = n0 + wc * 32 + ct * 16 + l16;
      int r0g = m0 + wr * 64 + rt * 16 + quad * 4;
      if (MODE == 0) {
        u16* C = (u16*)Cp;
        #pragma unroll
        for (int r = 0; r < 4; ++r)
          C[(size_t)(r0g + r) * N + col] = f2bf(acc[rt][ct][r] * scale);
      } else {
        float* C = (float*)Cp;
        float bv = bias[col];
        #pragma unroll
        for (int r = 0; r < 4; ++r)
          C[(size_t)(r0g + r) * N + col] = acc[rt][ct][r] + bv;
      }
    }
  }
}

// ---------------- K2: q-projection (blocks 0..511) + fused k/v (512..1535) ----
__global__ __launch_bounds__(256) void proj_kernel(const u16* __restrict__ xb,
    const u16* __restrict__ WqT, u16* __restrict__ qb,
    const u16* __restrict__ gctx, const u16* __restrict__ BkT,
    const u16* __restrict__ BvT, u16* __restrict__ Kp, u16* __restrict__ Vp) {
  __shared__ __align__(16) u16 As0[128 * 32], As1[128 * 32];
  __shared__ __align__(16) u16 Bs0[64 * 32], Bs1[64 * 32];
  int bid = blockIdx.x;
  if (bid < 512) {
    int n0 = (bid & 7) * 64, m0 = (bid >> 3) * 128;
    gemm128_body<0>(xb, WqT, qb, nullptr, m0, n0,
                    0.125f * 1.4426950408889634f, As0, As1, Bs0, Bs1);
    return;
  }
  // fused k+v projection, K=64, fragment-packed epilogues
  bid -= 512;
  const int Kd = 64;
  int lane = threadIdx.x & 63, wave = threadIdx.x >> 6;
  int quad = lane >> 4, l16 = lane & 15;
  int wr = wave >> 1, wc = wave & 1;
  int rowBase = (bid >> 3) * 64 + wr * 32;
  int colBase = (bid & 7) * 64 + wc * 32;
  facc ak[2][2] = {}, av[2][2] = {};
  const u16* a0 = gctx + (size_t)(rowBase + l16) * Kd + quad * 8;
  const u16* a1 = a0 + (size_t)16 * Kd;
  const u16* bk0 = BkT + (size_t)(colBase + l16) * Kd + quad * 8;
  const u16* bk1 = bk0 + (size_t)16 * Kd;
  const u16* bv0 = BvT + (size_t)(colBase + l16) * Kd + quad * 8;
  const u16* bv1 = bv0 + (size_t)16 * Kd;
  #pragma unroll
  for (int kk = 0; kk < Kd; kk += 32) {
    frag16 af0 = *(const frag16*)(a0 + kk);
    frag16 af1 = *(const frag16*)(a1 + kk);
    frag16 k0 = *(const frag16*)(bk0 + kk);
    frag16 k1 = *(const frag16*)(bk1 + kk);
    frag16 v0 = *(const frag16*)(bv0 + kk);
    frag16 v1 = *(const frag16*)(bv1 + kk);
    ak[0][0] = __builtin_amdgcn_mfma_f32_16x16x32_bf16(af0, k0, ak[0][0], 0, 0, 0);
    ak[0][1] = __builtin_amdgcn_mfma_f32_16x16x32_bf16(af0, k1, ak[0][1], 0, 0, 0);
    ak[1][0] = __builtin_amdgcn_mfma_f32_16x16x32_bf16(af1, k0, ak[1][0], 0, 0, 0);
    ak[1][1] = __builtin_amdgcn_mfma_f32_16x16x32_bf16(af1, k1, ak[1][1], 0, 0, 0);
    av[0][0] = __builtin_amdgcn_mfma_f32_16x16x32_bf16(af0, v0, av[0][0], 0, 0, 0);
    av[0][1] = __builtin_amdgcn_mfma_f32_16x16x32_bf16(af0, v1, av[0][1], 0, 0, 0);
    av[1][0] = __builtin_amdgcn_mfma_f32_16x16x32_bf16(af1, v0, av[1][0], 0, 0, 0);
    av[1][1] = __builtin_amdgcn_mfma_f32_16x16x32_bf16(af1, v1, av[1][1], 0, 0, 0);
  }
  #pragma unroll
  for (int rt = 0; rt < 2; ++rt) {
    #pragma unroll
    for (int ct = 0; ct < 2; ++ct) {
      int col = colBase + ct * 16 + l16;
      int r0g = rowBase + rt * 16 + quad * 4;
      int hh = col >> 6, d = col & 63;
      int b = r0g >> 11;
      #pragma unroll
      for (int r = 0; r < 4; ++r) {
        int m = (r0g + r) & 2047;
        size_t addr = ((((size_t)(b * 8 + hh) * 64 + (m >> 5)) * 4 + (d >> 4)) * 64
                       + ((d >> 3) & 1) * 32 + (m & 31)) * 8 + (d & 7);
        Kp[addr] = f2bf(ak[rt][ct][r]);
      }
      int m = r0g & 2047;
      size_t addr = ((((size_t)(b * 8 + hh) * 64 + (m >> 5)) * 4
                      + ((m >> 4) & 1) * 2 + (d >> 5)) * 64
                     + ((m >> 3) & 1) * 32 + (d & 31)) * 8 + (m & 7);
      ushort4 o;
      o.x = f2bf(av[rt][ct][0]); o.y = f2bf(av[rt][ct][1]);
      o.z = f2bf(av[rt][ct][2]); o.w = f2bf(av[rt][ct][3]);
      *(ushort4*)(Vp + addr) = o;
    }
  }
}

// ---------------- flash attention: LDS K/V staging, NJS-way key split ---------
// qb pre-scaled by 0.125*log2(e). Kp/Vp fragment-packed.
// Grid = 512*NJS blocks -> NJS*2 blocks/CU; occupancy cap rises with NJS.
// Opart: [NJS][8192][512] fp32, Lpart: [NJS][8192*8] fp32.
template<int NJS>
__global__ __launch_bounds__(256, 3) void attn_kernel(
    const u16* __restrict__ qb, const u16* __restrict__ Kp,
    const u16* __restrict__ Vp, float* __restrict__ Opart,
    float* __restrict__ Lpart) {
  const int TILES = 64 / NJS;         // 32-key tiles per block
  const int lane = threadIdx.x & 63, wave = threadIdx.x >> 6;
  const int l32 = lane & 31;
  const int hi = lane >> 5;           // half-wave index
  const int bid = blockIdx.x;
  const int bh = bid & 31;            // low bits -> XCD locality
  const int qblk = (bid >> 5) & 15;
  const int js = bid >> 9;
  const int b = bh >> 3, h = bh & 7;
  const int q0 = (qblk * 4 + wave) * 32;
  const int rowg = b * 2048 + q0 + l32;

  __shared__ __align__(16) u16 sK[2][2048], sV[2][2048];

  const u16* qp = qb + (size_t)rowg * 512 + h * 64 + hi * 8;
  frag16 qf0 = *(const frag16*)(qp);
  frag16 qf1 = *(const frag16*)(qp + 16);
  frag16 qf2 = *(const frag16*)(qp + 32);
  frag16 qf3 = *(const frag16*)(qp + 48);

  facc16 O0 = {}, O1 = {};
  float lsum = 0.f;

  const size_t ts = 2048;  // u16 per 32-key tile
  // per-lane staging source (16B per lane); wave stages fragment `wave`
  const u16* kpb = Kp + (size_t)(bh * 64 + js * TILES) * ts + wave * 512 + lane * 8;
  const u16* vpb = Vp + (size_t)(bh * 64 + js * TILES) * ts + wave * 512 + lane * 8;

  // preload tile 0 into buffer 0
  gld16(kpb, sK[0] + wave * 512);
  gld16(vpb, sV[0] + wave * 512);

  for (int t = 0; t < TILES; ++t) {
    const int p = t & 1;
    __syncthreads();                    // drains buffer-p loads
    if (t + 1 < TILES) {                // prefetch next tile into other buffer
      gld16(kpb + (size_t)(t + 1) * ts, sK[p ^ 1] + wave * 512);
      gld16(vpb + (size_t)(t + 1) * ts, sV[p ^ 1] + wave * 512);
    }

    frag16 kf[4], vf[4];
    #pragma unroll
    for (int i = 0; i < 4; ++i) {
      kf[i] = *(const frag16*)(sK[p] + i * 512 + lane * 8);
      vf[i] = *(const frag16*)(sV[p] + i * 512 + lane * 8);
    }

    facc16 S = {};
    S = __builtin_amdgcn_mfma_f32_32x32x16_bf16(kf[0], qf0, S, 0, 0, 0);
    S = __builtin_amdgcn_mfma_f32_32x32x16_bf16(kf[1], qf1, S, 0, 0, 0);
    S = __builtin_amdgcn_mfma_f32_32x32x16_bf16(kf[2], qf2, S, 0, 0, 0);
    S = __builtin_amdgcn_mfma_f32_32x32x16_bf16(kf[3], qf3, S, 0, 0, 0);

    float e[16];
    #pragma unroll
    for (int r = 0; r < 16; ++r) e[r] = __builtin_amdgcn_exp2f(S[r]);
    #pragma unroll
    for (int r = 0; r < 16; ++r) lsum += e[r];

    // S^T C-layout -> P B-operand layout: pack own, then half-wave dword swap.
    unsigned pu[2][4];
    #pragma unroll
    for (int c = 0; c < 2; ++c) {
      const float* ee = e + c * 8;
      unsigned L0 = pkbf(ee[0], ee[1]);
      unsigned L1 = pkbf(ee[2], ee[3]);
      unsigned H0 = pkbf(ee[4], ee[5]);
      unsigned H1 = pkbf(ee[6], ee[7]);
      unsigned Y0 = hi ? L0 : H0;
      unsigned Y1 = hi ? L1 : H1;
      unsigned X0 = (unsigned)__shfl_xor((int)Y0, 32);
      unsigned X1 = (unsigned)__shfl_xor((int)Y1, 32);
      pu[c][0] = hi ? X0 : L0;
      pu[c][1] = hi ? X1 : L1;
      pu[c][2] = hi ? H0 : X0;
      pu[c][3] = hi ? H1 : X1;
    }
    frag16 P0 = *(frag16*)&pu[0][0];
    frag16 P1 = *(frag16*)&pu[1][0];

    O0 = __builtin_amdgcn_mfma_f32_32x32x16_bf16(vf[0], P0, O0, 0, 0, 0);
    O0 = __builtin_amdgcn_mfma_f32_32x32x16_bf16(vf[2], P1, O0, 0, 0, 0);
    O1 = __builtin_amdgcn_mfma_f32_32x32x16_bf16(vf[1], P0, O1, 0, 0, 0);
    O1 = __builtin_amdgcn_mfma_f32_32x32x16_bf16(vf[3], P1, O1, 0, 0, 0);
  }

  lsum += __shfl_xor(lsum, 32);

  // O^T C-layout: col=q=l32, row=d = dt*32 + 8*(reg>>2) + 4*hi + (reg&3)
  float* op = Opart + ((size_t)js * 8192 + rowg) * 512 + h * 64;
  #pragma unroll
  for (int dt = 0; dt < 2; ++dt) {
    #pragma unroll
    for (int rq = 0; rq < 4; ++rq) {
      float4 v;
      if (dt == 0) { v.x = O0[rq*4]; v.y = O0[rq*4+1]; v.z = O0[rq*4+2]; v.w = O0[rq*4+3]; }
      else         { v.x = O1[rq*4]; v.y = O1[rq*4+1]; v.z = O1[rq*4+2]; v.w = O1[rq*4+3]; }
      int d0 = dt * 32 + 8 * rq + 4 * hi;
      *(float4*)(op + d0) = v;
    }
  }
  if (!hi) Lpart[(size_t)js * 65536 + (size_t)rowg * 8 + h] = lsum;
}

// ---------------- combine the NJS key-split partials -> bf16 ------------------
template<int NJS>
__global__ __launch_bounds__(256) void combine_kernel(const float* __restrict__ Opart,
    const float* __restrict__ Lpart, u16* __restrict__ ob) {
  int id = blockIdx.x * 256 + threadIdx.x;   // 8192*128
  int row = id >> 7, c4 = (id & 127) * 4;
  int hh = c4 >> 6;
  size_t o = (size_t)row * 512 + c4;
  float sx = 0.f, sy = 0.f, sz = 0.f, sw = 0.f, L = 0.f;
  #pragma unroll
  for (int s = 0; s < NJS; ++s) {
    const float4 v = *(const float4*)(Opart + (size_t)s * 8192 * 512 + o);
    sx += v.x; sy += v.y; sz += v.z; sw += v.w;
    L += Lpart[(size_t)s * 65536 + (size_t)row * 8 + hh];
  }
  float rl = 1.f / L;
  ushort4 u;
  u.x = f2bf(sx * rl);
  u.y = f2bf(sy * rl);
  u.z = f2bf(sz * rl);
  u.w = f2bf(sw * rl);
  *(ushort4*)(ob + o) = u;
}

// ---------------- out-projection GEMM ----------------------------------------
__global__ __launch_bounds__(256) void gemm_out(const u16* __restrict__ A,
    const u16* __restrict__ BT, float* __restrict__ C,
    const float* __restrict__ bias) {
  __shared__ __align__(16) u16 As0[128 * 32], As1[128 * 32];
  __shared__ __align__(16) u16 Bs0[64 * 32], Bs1[64 * 32];
  int n0 = (blockIdx.x & 7) * 64, m0 = (blockIdx.x >> 3) * 128;
  gemm128_body<2>(A, BT, C, bias, m0, n0, 1.f, As0, As1, Bs0, Bs1);
}

// ---------------- launch ------------------------------------------------------
extern "C" void kernel_launch(void* const* d_in, const int* in_sizes, int n_in,
                              void* d_out, int out_size, void* d_ws, size_t ws_size,
                              hipStream_t stream) {
  const float* x   = (const float*)d_in[0];
  const float* ctx = (const float*)d_in[1];
  const float* Wq  = (const float*)d_in[2];
  const float* Wk  = (const float*)d_in[3];
  const float* Wv  = (const float*)d_in[4];
  const float* W1  = (const float*)d_in[5];
  const float* b1  = (const float*)d_in[6];
  const float* W2  = (const float*)d_in[7];
  const float* b2  = (const float*)d_in[8];
  const float* Wo  = (const float*)d_in[9];
  const float* bo  = (const float*)d_in[10];
  float* out = (float*)d_out;

  char* ws = (char*)d_ws;
  size_t off = 0;
  auto alloc = [&](size_t bytes) {
    char* p = ws + off;
    off += (bytes + 255) & ~(size_t)255;
    return p;
  };
  u16* xb    = (u16*)alloc(8192ull * 512 * 2);
  u16* qb    = (u16*)alloc(8192ull * 512 * 2);
  u16* Kp    = (u16*)alloc(8192ull * 512 * 2);
  u16* Vp    = (u16*)alloc(8192ull * 512 * 2);
  u16* ob    = (u16*)alloc(8192ull * 512 * 2);
  u16* gctx  = (u16*)alloc(8192ull * 64 * 2);
  u16* WqT   = (u16*)alloc(512ull * 512 * 2);
  u16* WkT   = (u16*)alloc(512ull * 64 * 2);
  u16* WvT   = (u16*)alloc(512ull * 64 * 2);
  u16* WoT   = (u16*)alloc(512ull * 512 * 2);

  // key-split factor: 4 if the workspace can hold 4 fp32 partial slices
  const size_t base = off;
  const size_t perSlice = (8192ull * 512 + 65536ull) * 4 + 512;
  const bool big = (ws_size >= base + 4 * perSlice);
  float* Opart = (float*)alloc((big ? 4 : 2) * 8192ull * 512 * 4);
  float* Lpart = (float*)alloc((big ? 4 : 2) * 65536ull * 4);

  prep_gate_kernel<<<8448, 256, 0, stream>>>((const float4*)x, Wq, Wk, Wv, Wo,
                                             ctx, W1, b1, W2, b2,
                                             xb, WqT, WkT, WvT, WoT, gctx);
  proj_kernel<<<1536, 256, 0, stream>>>(xb, WqT, qb, gctx, WkT, WvT, Kp, Vp);
  if (big) {
    attn_kernel<4><<<2048, 256, 0, stream>>>(qb, Kp, Vp, Opart, Lpart);
    combine_kernel<4><<<4096, 256, 0, stream>>>(Opart, Lpart, ob);
  } else {
    attn_kernel<2><<<1024, 256, 0, stream>>>(qb, Kp, Vp, Opart, Lpart);
    combine_kernel<2><<<4096, 256, 0, stream>>>(Opart, Lpart, ob);
  }
  gemm_out<<<512, 256, 0, stream>>>(ob, WoT, out, bo);
}

// Round 11
// 172.220 us; speedup vs baseline: 1.0912x; 1.0912x over previous
//
#include <hip/hip_runtime.h>

typedef unsigned short u16;
typedef unsigned int u32;
using frag16 = __attribute__((ext_vector_type(8))) short;   // 8 x bf16 (4 VGPRs)
using facc   = __attribute__((ext_vector_type(4))) float;   // 4 x fp32 acc
using facc16 = __attribute__((ext_vector_type(16))) float;  // 16 x fp32 acc

#define DEV static __device__ __forceinline__

DEV u16 f2bf(float f) {
  union { float f; unsigned u; } v; v.f = f;
  unsigned r = v.u + 0x7fffu + ((v.u >> 16) & 1u);
  return (u16)(r >> 16);
}
DEV unsigned fbits(float f) {
  union { float f; unsigned u; } v; v.f = f;
  return v.u;
}
// pack two fp32 -> two bf16 (lo in low half), round-half-up
DEV unsigned pkbf(float lo, float hi) {
  return __builtin_amdgcn_perm(fbits(hi) + 0x8000u, fbits(lo) + 0x8000u, 0x07060302u);
}
// async global->LDS, 16B per lane. LDS dest = wave-uniform base + lane*16.
DEV void gld16(const u16* g, u16* l) {
  __builtin_amdgcn_global_load_lds(
      (__attribute__((address_space(1))) unsigned int*)(g),
      (__attribute__((address_space(3))) unsigned int*)(l), 16, 0, 0);
}

// ---------------- K1: x cvt (0..4095) + weight transposes (..6399) + gate ----
__global__ __launch_bounds__(256) void prep_gate_kernel(const float4* __restrict__ x,
    const float* __restrict__ Wq, const float* __restrict__ Wk,
    const float* __restrict__ Wv, const float* __restrict__ Wo,
    const float* __restrict__ ctx, const float* __restrict__ W1,
    const float* __restrict__ b1, const float* __restrict__ W2,
    const float* __restrict__ b2,
    u16* __restrict__ xb, u16* __restrict__ WqT, u16* __restrict__ WkT,
    u16* __restrict__ WvT, u16* __restrict__ WoT, u16* __restrict__ gctx) {
  int bid = blockIdx.x;
  if (bid < 4096) {
    int id = bid * 256 + threadIdx.x;
    float4 v = x[id];
    ushort4 o;
    o.x = f2bf(v.x); o.y = f2bf(v.y); o.z = f2bf(v.z); o.w = f2bf(v.w);
    *(ushort4*)(xb + (size_t)id * 4) = o;
  } else if (bid < 6400) {
    int id = (bid - 4096) * 256 + threadIdx.x;   // 589824 total
    const float* W; u16* WT; int K, idx;
    if (id < 262144)      { W = Wq; WT = WqT; K = 512; idx = id; }
    else if (id < 294912) { W = Wk; WT = WkT; K = 64;  idx = id - 262144; }
    else if (id < 327680) { W = Wv; WT = WvT; K = 64;  idx = id - 294912; }
    else                  { W = Wo; WT = WoT; K = 512; idx = id - 327680; }
    int n = idx / K, k = idx - n * K;
    WT[idx] = f2bf(W[k * 512 + n]);
  } else {
    // gate: gctx = bf16(ctx * sigmoid(relu(ctx@W1+b1)@W2+b2))
    int wave = threadIdx.x >> 6, lane = threadIdx.x & 63;
    int row = (bid - 6400) * 4 + wave;          // 8192 rows
    __shared__ float sc[4][64];
    float cv = ctx[(size_t)row * 64 + lane];
    sc[wave][lane] = cv;
    __syncthreads();
    float h = 0.f;
    if (lane < 32) {
      h = b1[lane];
      #pragma unroll
      for (int i = 0; i < 64; ++i) h += sc[wave][i] * W1[i * 32 + lane];
      h = fmaxf(h, 0.f) * W2[lane];
    }
    #pragma unroll
    for (int off = 32; off; off >>= 1) h += __shfl_xor(h, off);
    float g = 1.f / (1.f + __expf(-(h + b2[0])));
    gctx[(size_t)row * 64 + lane] = f2bf(cv * g);
  }
}

// ---------------- big GEMM body: 128x64 tile, BK=64, gld16 --------------------
// MODE 0: bf16 out * scale. MODE 2: fp32 out + bias.
template<int MODE>
DEV void gemm128_body(const u16* __restrict__ A, const u16* __restrict__ BT,
                      void* __restrict__ Cp, const float* __restrict__ bias,
                      int m0, int n0, float scale,
                      u16* As0, u16* As1, u16* Bs0, u16* Bs1) {
  const int K = 512, N = 512;
  const int lane = threadIdx.x & 63, wave = threadIdx.x >> 6;
  const int quad = lane >> 4, l16 = lane & 15;
  const int wr = wave >> 1, wc = wave & 1;

  const u16* gA = A + (size_t)(m0 + wave * 32 + (lane >> 2)) * K + (lane & 3) * 8;
  const u16* gB = BT + (size_t)(n0 + wave * 16 + (lane >> 2)) * K + (lane & 3) * 8;

  facc acc[4][2] = {};

  for (int k0 = 0; k0 < K; k0 += 64) {
    if (k0) __syncthreads();
    gld16(gA + k0,           As0 + wave * 1024);
    gld16(gA + 16 * K + k0,  As0 + wave * 1024 + 512);
    gld16(gA + k0 + 32,          As1 + wave * 1024);
    gld16(gA + 16 * K + k0 + 32, As1 + wave * 1024 + 512);
    gld16(gB + k0,      Bs0 + wave * 512);
    gld16(gB + k0 + 32, Bs1 + wave * 512);
    __syncthreads();

    #pragma unroll
    for (int hh = 0; hh < 2; ++hh) {
      const u16* Ah = hh ? As1 : As0;
      const u16* Bh = hh ? Bs1 : Bs0;
      frag16 af[4], bf[2];
      #pragma unroll
      for (int rt = 0; rt < 4; ++rt)
        af[rt] = *(const frag16*)(Ah + (wr * 64 + rt * 16 + l16) * 32 + quad * 8);
      #pragma unroll
      for (int ct = 0; ct < 2; ++ct)
        bf[ct] = *(const frag16*)(Bh + (wc * 32 + ct * 16 + l16) * 32 + quad * 8);
      #pragma unroll
      for (int rt = 0; rt < 4; ++rt)
        #pragma unroll
        for (int ct = 0; ct < 2; ++ct)
          acc[rt][ct] = __builtin_amdgcn_mfma_f32_16x16x32_bf16(af[rt], bf[ct], acc[rt][ct], 0, 0, 0);
    }
  }

  #pragma unroll
  for (int rt = 0; rt < 4; ++rt) {
    #pragma unroll
    for (int ct = 0; ct < 2; ++ct) {
      int col = n0 + wc * 32 + ct * 16 + l16;
      int r0g = m0 + wr * 64 + rt * 16 + quad * 4;
      if (MODE == 0) {
        u16* C = (u16*)Cp;
        #pragma unroll
        for (int r = 0; r < 4; ++r)
          C[(size_t)(r0g + r) * N + col] = f2bf(acc[rt][ct][r] * scale);
      } else {
        float* C = (float*)Cp;
        float bv = bias[col];
        #pragma unroll
        for (int r = 0; r < 4; ++r)
          C[(size_t)(r0g + r) * N + col] = acc[rt][ct][r] + bv;
      }
    }
  }
}

// ---------------- K2: q-projection (blocks 0..511) + fused k/v (512..1535) ----
__global__ __launch_bounds__(256) void proj_kernel(const u16* __restrict__ xb,
    const u16* __restrict__ WqT, u16* __restrict__ qb,
    const u16* __restrict__ gctx, const u16* __restrict__ BkT,
    const u16* __restrict__ BvT, u16* __restrict__ Kp, u16* __restrict__ Vp) {
  __shared__ __align__(16) u16 As0[128 * 32], As1[128 * 32];
  __shared__ __align__(16) u16 Bs0[64 * 32], Bs1[64 * 32];
  int bid = blockIdx.x;
  if (bid < 512) {
    int n0 = (bid & 7) * 64, m0 = (bid >> 3) * 128;
    gemm128_body<0>(xb, WqT, qb, nullptr, m0, n0,
                    0.125f * 1.4426950408889634f, As0, As1, Bs0, Bs1);
    return;
  }
  // fused k+v projection, K=64, fragment-packed epilogues
  bid -= 512;
  const int Kd = 64;
  int lane = threadIdx.x & 63, wave = threadIdx.x >> 6;
  int quad = lane >> 4, l16 = lane & 15;
  int wr = wave >> 1, wc = wave & 1;
  int rowBase = (bid >> 3) * 64 + wr * 32;
  int colBase = (bid & 7) * 64 + wc * 32;
  facc ak[2][2] = {}, av[2][2] = {};
  const u16* a0 = gctx + (size_t)(rowBase + l16) * Kd + quad * 8;
  const u16* a1 = a0 + (size_t)16 * Kd;
  const u16* bk0 = BkT + (size_t)(colBase + l16) * Kd + quad * 8;
  const u16* bk1 = bk0 + (size_t)16 * Kd;
  const u16* bv0 = BvT + (size_t)(colBase + l16) * Kd + quad * 8;
  const u16* bv1 = bv0 + (size_t)16 * Kd;
  #pragma unroll
  for (int kk = 0; kk < Kd; kk += 32) {
    frag16 af0 = *(const frag16*)(a0 + kk);
    frag16 af1 = *(const frag16*)(a1 + kk);
    frag16 k0 = *(const frag16*)(bk0 + kk);
    frag16 k1 = *(const frag16*)(bk1 + kk);
    frag16 v0 = *(const frag16*)(bv0 + kk);
    frag16 v1 = *(const frag16*)(bv1 + kk);
    ak[0][0] = __builtin_amdgcn_mfma_f32_16x16x32_bf16(af0, k0, ak[0][0], 0, 0, 0);
    ak[0][1] = __builtin_amdgcn_mfma_f32_16x16x32_bf16(af0, k1, ak[0][1], 0, 0, 0);
    ak[1][0] = __builtin_amdgcn_mfma_f32_16x16x32_bf16(af1, k0, ak[1][0], 0, 0, 0);
    ak[1][1] = __builtin_amdgcn_mfma_f32_16x16x32_bf16(af1, k1, ak[1][1], 0, 0, 0);
    av[0][0] = __builtin_amdgcn_mfma_f32_16x16x32_bf16(af0, v0, av[0][0], 0, 0, 0);
    av[0][1] = __builtin_amdgcn_mfma_f32_16x16x32_bf16(af0, v1, av[0][1], 0, 0, 0);
    av[1][0] = __builtin_amdgcn_mfma_f32_16x16x32_bf16(af1, v0, av[1][0], 0, 0, 0);
    av[1][1] = __builtin_amdgcn_mfma_f32_16x16x32_bf16(af1, v1, av[1][1], 0, 0, 0);
  }
  #pragma unroll
  for (int rt = 0; rt < 2; ++rt) {
    #pragma unroll
    for (int ct = 0; ct < 2; ++ct) {
      int col = colBase + ct * 16 + l16;
      int r0g = rowBase + rt * 16 + quad * 4;
      int hh = col >> 6, d = col & 63;
      int b = r0g >> 11;
      #pragma unroll
      for (int r = 0; r < 4; ++r) {
        int m = (r0g + r) & 2047;
        size_t addr = ((((size_t)(b * 8 + hh) * 64 + (m >> 5)) * 4 + (d >> 4)) * 64
                       + ((d >> 3) & 1) * 32 + (m & 31)) * 8 + (d & 7);
        Kp[addr] = f2bf(ak[rt][ct][r]);
      }
      int m = r0g & 2047;
      size_t addr = ((((size_t)(b * 8 + hh) * 64 + (m >> 5)) * 4
                      + ((m >> 4) & 1) * 2 + (d >> 5)) * 64
                     + ((m >> 3) & 1) * 32 + (d & 31)) * 8 + (m & 7);
      ushort4 o;
      o.x = f2bf(av[rt][ct][0]); o.y = f2bf(av[rt][ct][1]);
      o.z = f2bf(av[rt][ct][2]); o.w = f2bf(av[rt][ct][3]);
      *(ushort4*)(Vp + addr) = o;
    }
  }
}

// ---------------- flash attention: NJS=1, 2-tile ILP, LDS group staging -------
// qb pre-scaled by 0.125*log2(e). Kp/Vp fragment-packed. Each block owns all
// 2048 keys for its 128 q-rows -> writes final bf16 ob directly (no partials,
// no combine kernel). Per loop iter: TWO independent 32-key tile streams
// (separate S/e/P registers) -> 2x dependency-chain ILP; one barrier per 2
// tiles. LDS: 2 groups x (8KB K + 8KB V), double-buffered.
__global__ __launch_bounds__(256, 2) void attn_kernel(
    const u16* __restrict__ qb, const u16* __restrict__ Kp,
    const u16* __restrict__ Vp, u16* __restrict__ ob) {
  const int lane = threadIdx.x & 63, wave = threadIdx.x >> 6;
  const int l32 = lane & 31;
  const int hi = lane >> 5;           // half-wave index
  const int bid = blockIdx.x;
  const int bh = bid & 31;            // low bits -> XCD locality
  const int qblk = bid >> 5;          // 0..15
  const int b = bh >> 3, h = bh & 7;
  const int q0 = (qblk * 4 + wave) * 32;
  const int rowg = b * 2048 + q0 + l32;

  __shared__ __align__(16) u16 sK[2][2][2048], sV[2][2][2048];   // [buf][tile][..]

  const u16* qp = qb + (size_t)rowg * 512 + h * 64 + hi * 8;
  frag16 qf0 = *(const frag16*)(qp);
  frag16 qf1 = *(const frag16*)(qp + 16);
  frag16 qf2 = *(const frag16*)(qp + 32);
  frag16 qf3 = *(const frag16*)(qp + 48);

  facc16 O0 = {}, O1 = {};
  float lsum = 0.f;

  const size_t ts = 2048;  // u16 per 32-key tile
  const u16* kpb = Kp + (size_t)(bh * 64) * ts + wave * 512 + lane * 8;
  const u16* vpb = Vp + (size_t)(bh * 64) * ts + wave * 512 + lane * 8;

  // preload group 0 (tiles 0,1) into buffer 0
  gld16(kpb,      sK[0][0] + wave * 512);
  gld16(kpb + ts, sK[0][1] + wave * 512);
  gld16(vpb,      sV[0][0] + wave * 512);
  gld16(vpb + ts, sV[0][1] + wave * 512);

  for (int g = 0; g < 32; ++g) {
    const int p = g & 1;
    __syncthreads();                    // drains buffer-p loads
    if (g + 1 < 32) {                   // prefetch next group
      const size_t t2 = (size_t)(2 * g + 2) * ts;
      gld16(kpb + t2,      sK[p ^ 1][0] + wave * 512);
      gld16(kpb + t2 + ts, sK[p ^ 1][1] + wave * 512);
      gld16(vpb + t2,      sV[p ^ 1][0] + wave * 512);
      gld16(vpb + t2 + ts, sV[p ^ 1][1] + wave * 512);
    }

    frag16 kfa[4], kfb[4];
    #pragma unroll
    for (int i = 0; i < 4; ++i) {
      kfa[i] = *(const frag16*)(sK[p][0] + i * 512 + lane * 8);
      kfb[i] = *(const frag16*)(sK[p][1] + i * 512 + lane * 8);
    }

    // two independent S chains (ILP x2)
    facc16 Sa = {}, Sb = {};
    Sa = __builtin_amdgcn_mfma_f32_32x32x16_bf16(kfa[0], qf0, Sa, 0, 0, 0);
    Sb = __builtin_amdgcn_mfma_f32_32x32x16_bf16(kfb[0], qf0, Sb, 0, 0, 0);
    Sa = __builtin_amdgcn_mfma_f32_32x32x16_bf16(kfa[1], qf1, Sa, 0, 0, 0);
    Sb = __builtin_amdgcn_mfma_f32_32x32x16_bf16(kfb[1], qf1, Sb, 0, 0, 0);
    Sa = __builtin_amdgcn_mfma_f32_32x32x16_bf16(kfa[2], qf2, Sa, 0, 0, 0);
    Sb = __builtin_amdgcn_mfma_f32_32x32x16_bf16(kfb[2], qf2, Sb, 0, 0, 0);
    Sa = __builtin_amdgcn_mfma_f32_32x32x16_bf16(kfa[3], qf3, Sa, 0, 0, 0);
    Sb = __builtin_amdgcn_mfma_f32_32x32x16_bf16(kfb[3], qf3, Sb, 0, 0, 0);

    float ea[16], eb[16];
    #pragma unroll
    for (int r = 0; r < 16; ++r) { ea[r] = __builtin_amdgcn_exp2f(Sa[r]);
                                   eb[r] = __builtin_amdgcn_exp2f(Sb[r]); }
    #pragma unroll
    for (int r = 0; r < 16; ++r) lsum += ea[r] + eb[r];

    // S^T C-layout -> P B-operand: pack own, half-wave dword swap (per stream)
    unsigned pua[2][4], pub[2][4];
    #pragma unroll
    for (int c = 0; c < 2; ++c) {
      {
        const float* ee = ea + c * 8;
        unsigned L0 = pkbf(ee[0], ee[1]);
        unsigned L1 = pkbf(ee[2], ee[3]);
        unsigned H0 = pkbf(ee[4], ee[5]);
        unsigned H1 = pkbf(ee[6], ee[7]);
        unsigned Y0 = hi ? L0 : H0;
        unsigned Y1 = hi ? L1 : H1;
        unsigned X0 = (unsigned)__shfl_xor((int)Y0, 32);
        unsigned X1 = (unsigned)__shfl_xor((int)Y1, 32);
        pua[c][0] = hi ? X0 : L0;
        pua[c][1] = hi ? X1 : L1;
        pua[c][2] = hi ? H0 : X0;
        pua[c][3] = hi ? H1 : X1;
      }
      {
        const float* ee = eb + c * 8;
        unsigned L0 = pkbf(ee[0], ee[1]);
        unsigned L1 = pkbf(ee[2], ee[3]);
        unsigned H0 = pkbf(ee[4], ee[5]);
        unsigned H1 = pkbf(ee[6], ee[7]);
        unsigned Y0 = hi ? L0 : H0;
        unsigned Y1 = hi ? L1 : H1;
        unsigned X0 = (unsigned)__shfl_xor((int)Y0, 32);
        unsigned X1 = (unsigned)__shfl_xor((int)Y1, 32);
        pub[c][0] = hi ? X0 : L0;
        pub[c][1] = hi ? X1 : L1;
        pub[c][2] = hi ? H0 : X0;
        pub[c][3] = hi ? H1 : X1;
      }
    }
    frag16 Pa0 = *(frag16*)&pua[0][0];
    frag16 Pa1 = *(frag16*)&pua[1][0];
    frag16 Pb0 = *(frag16*)&pub[0][0];
    frag16 Pb1 = *(frag16*)&pub[1][0];

    frag16 vfa[4], vfb[4];
    #pragma unroll
    for (int i = 0; i < 4; ++i) {
      vfa[i] = *(const frag16*)(sV[p][0] + i * 512 + lane * 8);
      vfb[i] = *(const frag16*)(sV[p][1] + i * 512 + lane * 8);
    }

    O0 = __builtin_amdgcn_mfma_f32_32x32x16_bf16(vfa[0], Pa0, O0, 0, 0, 0);
    O1 = __builtin_amdgcn_mfma_f32_32x32x16_bf16(vfa[1], Pa0, O1, 0, 0, 0);
    O0 = __builtin_amdgcn_mfma_f32_32x32x16_bf16(vfa[2], Pa1, O0, 0, 0, 0);
    O1 = __builtin_amdgcn_mfma_f32_32x32x16_bf16(vfa[3], Pa1, O1, 0, 0, 0);
    O0 = __builtin_amdgcn_mfma_f32_32x32x16_bf16(vfb[0], Pb0, O0, 0, 0, 0);
    O1 = __builtin_amdgcn_mfma_f32_32x32x16_bf16(vfb[1], Pb0, O1, 0, 0, 0);
    O0 = __builtin_amdgcn_mfma_f32_32x32x16_bf16(vfb[2], Pb1, O0, 0, 0, 0);
    O1 = __builtin_amdgcn_mfma_f32_32x32x16_bf16(vfb[3], Pb1, O1, 0, 0, 0);
  }

  lsum += __shfl_xor(lsum, 32);
  float rinv = 1.0f / lsum;             // per lane: L for query q = l32

  // O^T C-layout: col=q=l32, row=d = dt*32 + 8*rq + 4*hi + (reg&3). Final bf16.
  u16* op = ob + (size_t)rowg * 512 + h * 64;
  #pragma unroll
  for (int dt = 0; dt < 2; ++dt) {
    #pragma unroll
    for (int rq = 0; rq < 4; ++rq) {
      float v0, v1, v2, v3;
      if (dt == 0) { v0 = O0[rq*4]; v1 = O0[rq*4+1]; v2 = O0[rq*4+2]; v3 = O0[rq*4+3]; }
      else         { v0 = O1[rq*4]; v1 = O1[rq*4+1]; v2 = O1[rq*4+2]; v3 = O1[rq*4+3]; }
      uint2 pk;
      pk.x = pkbf(v0 * rinv, v1 * rinv);
      pk.y = pkbf(v2 * rinv, v3 * rinv);
      int d0 = dt * 32 + 8 * rq + 4 * hi;
      *(uint2*)(op + d0) = pk;
    }
  }
}

// ---------------- out-projection GEMM ----------------------------------------
__global__ __launch_bounds__(256) void gemm_out(const u16* __restrict__ A,
    const u16* __restrict__ BT, float* __restrict__ C,
    const float* __restrict__ bias) {
  __shared__ __align__(16) u16 As0[128 * 32], As1[128 * 32];
  __shared__ __align__(16) u16 Bs0[64 * 32], Bs1[64 * 32];
  int n0 = (blockIdx.x & 7) * 64, m0 = (blockIdx.x >> 3) * 128;
  gemm128_body<2>(A, BT, C, bias, m0, n0, 1.f, As0, As1, Bs0, Bs1);
}

// ---------------- launch ------------------------------------------------------
extern "C" void kernel_launch(void* const* d_in, const int* in_sizes, int n_in,
                              void* d_out, int out_size, void* d_ws, size_t ws_size,
                              hipStream_t stream) {
  const float* x   = (const float*)d_in[0];
  const float* ctx = (const float*)d_in[1];
  const float* Wq  = (const float*)d_in[2];
  const float* Wk  = (const float*)d_in[3];
  const float* Wv  = (const float*)d_in[4];
  const float* W1  = (const float*)d_in[5];
  const float* b1  = (const float*)d_in[6];
  const float* W2  = (const float*)d_in[7];
  const float* b2  = (const float*)d_in[8];
  const float* Wo  = (const float*)d_in[9];
  const float* bo  = (const float*)d_in[10];
  float* out = (float*)d_out;

  char* ws = (char*)d_ws;
  size_t off = 0;
  auto alloc = [&](size_t bytes) {
    char* p = ws + off;
    off += (bytes + 255) & ~(size_t)255;
    return p;
  };
  u16* xb    = (u16*)alloc(8192ull * 512 * 2);
  u16* qb    = (u16*)alloc(8192ull * 512 * 2);
  u16* Kp    = (u16*)alloc(8192ull * 512 * 2);
  u16* Vp    = (u16*)alloc(8192ull * 512 * 2);
  u16* ob    = (u16*)alloc(8192ull * 512 * 2);
  u16* gctx  = (u16*)alloc(8192ull * 64 * 2);
  u16* WqT   = (u16*)alloc(512ull * 512 * 2);
  u16* WkT   = (u16*)alloc(512ull * 64 * 2);
  u16* WvT   = (u16*)alloc(512ull * 64 * 2);
  u16* WoT   = (u16*)alloc(512ull * 512 * 2);

  prep_gate_kernel<<<8448, 256, 0, stream>>>((const float4*)x, Wq, Wk, Wv, Wo,
                                             ctx, W1, b1, W2, b2,
                                             xb, WqT, WkT, WvT, WoT, gctx);
  proj_kernel<<<1536, 256, 0, stream>>>(xb, WqT, qb, gctx, WkT, WvT, Kp, Vp);
  attn_kernel<<<512, 256, 0, stream>>>(qb, Kp, Vp, ob);
  gemm_out<<<512, 256, 0, stream>>>(ob, WoT, out, bo);
}

// Round 12
// 166.980 us; speedup vs baseline: 1.1254x; 1.0314x over previous
//
#include <hip/hip_runtime.h>

typedef unsigned short u16;
typedef unsigned int u32;
using frag16 = __attribute__((ext_vector_type(8))) short;   // 8 x bf16 (4 VGPRs)
using facc   = __attribute__((ext_vector_type(4))) float;   // 4 x fp32 acc
using facc16 = __attribute__((ext_vector_type(16))) float;  // 16 x fp32 acc

#define DEV static __device__ __forceinline__

DEV u16 f2bf(float f) {
  union { float f; unsigned u; } v; v.f = f;
  unsigned r = v.u + 0x7fffu + ((v.u >> 16) & 1u);
  return (u16)(r >> 16);
}
DEV unsigned fbits(float f) {
  union { float f; unsigned u; } v; v.f = f;
  return v.u;
}
// pack two fp32 -> two bf16 (lo in low half), round-half-up
DEV unsigned pkbf(float lo, float hi) {
  return __builtin_amdgcn_perm(fbits(hi) + 0x8000u, fbits(lo) + 0x8000u, 0x07060302u);
}
// truncating pack (no rounding adds) -- used for P where the bias cancels
// between numerator and the MFMA-computed denominator.
DEV unsigned pkbf_t(float lo, float hi) {
  return __builtin_amdgcn_perm(fbits(hi), fbits(lo), 0x07060302u);
}
// async global->LDS, 16B per lane. LDS dest = wave-uniform base + lane*16.
DEV void gld16(const u16* g, u16* l) {
  __builtin_amdgcn_global_load_lds(
      (__attribute__((address_space(1))) unsigned int*)(g),
      (__attribute__((address_space(3))) unsigned int*)(l), 16, 0, 0);
}

// ---------------- K1: x cvt (0..4095) + LDS-coalesced wtrans + gate ----------
__global__ __launch_bounds__(256) void prep_gate_kernel(const float4* __restrict__ x,
    const float* __restrict__ Wq, const float* __restrict__ Wk,
    const float* __restrict__ Wv, const float* __restrict__ Wo,
    const float* __restrict__ ctx, const float* __restrict__ W1,
    const float* __restrict__ b1, const float* __restrict__ W2,
    const float* __restrict__ b2,
    u16* __restrict__ xb, u16* __restrict__ WqT, u16* __restrict__ WkT,
    u16* __restrict__ WvT, u16* __restrict__ WoT, u16* __restrict__ gctx) {
  int bid = blockIdx.x;
  if (bid < 4096) {
    int id = bid * 256 + threadIdx.x;
    float4 v = x[id];
    ushort4 o;
    o.x = f2bf(v.x); o.y = f2bf(v.y); o.z = f2bf(v.z); o.w = f2bf(v.w);
    *(ushort4*)(xb + (size_t)id * 4) = o;
  } else if (bid < 4240) {
    // 64x64 tile transpose via LDS: coalesced read AND write
    int job = bid - 4096;  // 0..143
    const float* W; u16* WT; int K, tile;
    if (job < 64)      { W = Wq; WT = WqT; K = 512; tile = job; }
    else if (job < 72) { W = Wk; WT = WkT; K = 64;  tile = job - 64; }
    else if (job < 80) { W = Wv; WT = WvT; K = 64;  tile = job - 72; }
    else               { W = Wo; WT = WoT; K = 512; tile = job - 80; }
    int tilesK = K >> 6;
    int tr = tile % tilesK, tc = tile / tilesK;
    __shared__ float tl[64][65];
    int c = threadIdx.x & 63, r4 = threadIdx.x >> 6;
    #pragma unroll
    for (int it = 0; it < 16; ++it) {
      int kk = it * 4 + r4;
      tl[kk][c] = W[(size_t)(tr * 64 + kk) * 512 + tc * 64 + c];
    }
    __syncthreads();
    #pragma unroll
    for (int it = 0; it < 16; ++it) {
      int nn = it * 4 + r4;
      WT[(size_t)(tc * 64 + nn) * K + tr * 64 + c] = f2bf(tl[c][nn]);
    }
  } else {
    // gate: gctx = bf16(ctx * sigmoid(relu(ctx@W1+b1)@W2+b2))
    int wave = threadIdx.x >> 6, lane = threadIdx.x & 63;
    int row = (bid - 4240) * 4 + wave;          // 8192 rows
    __shared__ float sc[4][64];
    float cv = ctx[(size_t)row * 64 + lane];
    sc[wave][lane] = cv;
    __syncthreads();
    float h = 0.f;
    if (lane < 32) {
      h = b1[lane];
      #pragma unroll
      for (int i = 0; i < 64; ++i) h += sc[wave][i] * W1[i * 32 + lane];
      h = fmaxf(h, 0.f) * W2[lane];
    }
    #pragma unroll
    for (int off = 32; off; off >>= 1) h += __shfl_xor(h, off);
    float g = 1.f / (1.f + __expf(-(h + b2[0])));
    gctx[(size_t)row * 64 + lane] = f2bf(cv * g);
  }
}

// ---------------- big GEMM body: 128x64 tile, BK=64, gld16 --------------------
// MODE 0: bf16 out * scale. MODE 2: fp32 out + bias.
template<int MODE>
DEV void gemm128_body(const u16* __restrict__ A, const u16* __restrict__ BT,
                      void* __restrict__ Cp, const float* __restrict__ bias,
                      int m0, int n0, float scale,
                      u16* As0, u16* As1, u16* Bs0, u16* Bs1) {
  const int K = 512, N = 512;
  const int lane = threadIdx.x & 63, wave = threadIdx.x >> 6;
  const int quad = lane >> 4, l16 = lane & 15;
  const int wr = wave >> 1, wc = wave & 1;

  const u16* gA = A + (size_t)(m0 + wave * 32 + (lane >> 2)) * K + (lane & 3) * 8;
  const u16* gB = BT + (size_t)(n0 + wave * 16 + (lane >> 2)) * K + (lane & 3) * 8;

  facc acc[4][2] = {};

  for (int k0 = 0; k0 < K; k0 += 64) {
    if (k0) __syncthreads();
    gld16(gA + k0,           As0 + wave * 1024);
    gld16(gA + 16 * K + k0,  As0 + wave * 1024 + 512);
    gld16(gA + k0 + 32,          As1 + wave * 1024);
    gld16(gA + 16 * K + k0 + 32, As1 + wave * 1024 + 512);
    gld16(gB + k0,      Bs0 + wave * 512);
    gld16(gB + k0 + 32, Bs1 + wave * 512);
    __syncthreads();

    #pragma unroll
    for (int hh = 0; hh < 2; ++hh) {
      const u16* Ah = hh ? As1 : As0;
      const u16* Bh = hh ? Bs1 : Bs0;
      frag16 af[4], bf[2];
      #pragma unroll
      for (int rt = 0; rt < 4; ++rt)
        af[rt] = *(const frag16*)(Ah + (wr * 64 + rt * 16 + l16) * 32 + quad * 8);
      #pragma unroll
      for (int ct = 0; ct < 2; ++ct)
        bf[ct] = *(const frag16*)(Bh + (wc * 32 + ct * 16 + l16) * 32 + quad * 8);
      #pragma unroll
      for (int rt = 0; rt < 4; ++rt)
        #pragma unroll
        for (int ct = 0; ct < 2; ++ct)
          acc[rt][ct] = __builtin_amdgcn_mfma_f32_16x16x32_bf16(af[rt], bf[ct], acc[rt][ct], 0, 0, 0);
    }
  }

  #pragma unroll
  for (int rt = 0; rt < 4; ++rt) {
    #pragma unroll
    for (int ct = 0; ct < 2; ++ct) {
      int col = n0 + wc * 32 + ct * 16 + l16;
      int r0g = m0 + wr * 64 + rt * 16 + quad * 4;
      if (MODE == 0) {
        u16* C = (u16*)Cp;
        #pragma unroll
        for (int r = 0; r < 4; ++r)
          C[(size_t)(r0g + r) * N + col] = f2bf(acc[rt][ct][r] * scale);
      } else {
        float* C = (float*)Cp;
        float bv = bias[col];
        #pragma unroll
        for (int r = 0; r < 4; ++r)
          C[(size_t)(r0g + r) * N + col] = acc[rt][ct][r] + bv;
      }
    }
  }
}

// ---------------- K2: q-projection (blocks 0..511) + fused k/v (512..1535) ----
__global__ __launch_bounds__(256) void proj_kernel(const u16* __restrict__ xb,
    const u16* __restrict__ WqT, u16* __restrict__ qb,
    const u16* __restrict__ gctx, const u16* __restrict__ BkT,
    const u16* __restrict__ BvT, u16* __restrict__ Kp, u16* __restrict__ Vp) {
  __shared__ __align__(16) u16 As0[128 * 32], As1[128 * 32];
  __shared__ __align__(16) u16 Bs0[64 * 32], Bs1[64 * 32];
  int bid = blockIdx.x;
  if (bid < 512) {
    int n0 = (bid & 7) * 64, m0 = (bid >> 3) * 128;
    gemm128_body<0>(xb, WqT, qb, nullptr, m0, n0,
                    0.125f * 1.4426950408889634f, As0, As1, Bs0, Bs1);
    return;
  }
  // fused k+v projection, K=64, fragment-packed epilogues
  bid -= 512;
  const int Kd = 64;
  int lane = threadIdx.x & 63, wave = threadIdx.x >> 6;
  int quad = lane >> 4, l16 = lane & 15;
  int wr = wave >> 1, wc = wave & 1;
  int rowBase = (bid >> 3) * 64 + wr * 32;
  int colBase = (bid & 7) * 64 + wc * 32;
  facc ak[2][2] = {}, av[2][2] = {};
  const u16* a0 = gctx + (size_t)(rowBase + l16) * Kd + quad * 8;
  const u16* a1 = a0 + (size_t)16 * Kd;
  const u16* bk0 = BkT + (size_t)(colBase + l16) * Kd + quad * 8;
  const u16* bk1 = bk0 + (size_t)16 * Kd;
  const u16* bv0 = BvT + (size_t)(colBase + l16) * Kd + quad * 8;
  const u16* bv1 = bv0 + (size_t)16 * Kd;
  #pragma unroll
  for (int kk = 0; kk < Kd; kk += 32) {
    frag16 af0 = *(const frag16*)(a0 + kk);
    frag16 af1 = *(const frag16*)(a1 + kk);
    frag16 k0 = *(const frag16*)(bk0 + kk);
    frag16 k1 = *(const frag16*)(bk1 + kk);
    frag16 v0 = *(const frag16*)(bv0 + kk);
    frag16 v1 = *(const frag16*)(bv1 + kk);
    ak[0][0] = __builtin_amdgcn_mfma_f32_16x16x32_bf16(af0, k0, ak[0][0], 0, 0, 0);
    ak[0][1] = __builtin_amdgcn_mfma_f32_16x16x32_bf16(af0, k1, ak[0][1], 0, 0, 0);
    ak[1][0] = __builtin_amdgcn_mfma_f32_16x16x32_bf16(af1, k0, ak[1][0], 0, 0, 0);
    ak[1][1] = __builtin_amdgcn_mfma_f32_16x16x32_bf16(af1, k1, ak[1][1], 0, 0, 0);
    av[0][0] = __builtin_amdgcn_mfma_f32_16x16x32_bf16(af0, v0, av[0][0], 0, 0, 0);
    av[0][1] = __builtin_amdgcn_mfma_f32_16x16x32_bf16(af0, v1, av[0][1], 0, 0, 0);
    av[1][0] = __builtin_amdgcn_mfma_f32_16x16x32_bf16(af1, v0, av[1][0], 0, 0, 0);
    av[1][1] = __builtin_amdgcn_mfma_f32_16x16x32_bf16(af1, v1, av[1][1], 0, 0, 0);
  }
  #pragma unroll
  for (int rt = 0; rt < 2; ++rt) {
    #pragma unroll
    for (int ct = 0; ct < 2; ++ct) {
      int col = colBase + ct * 16 + l16;
      int r0g = rowBase + rt * 16 + quad * 4;
      int hh = col >> 6, d = col & 63;
      int b = r0g >> 11;
      #pragma unroll
      for (int r = 0; r < 4; ++r) {
        int m = (r0g + r) & 2047;
        size_t addr = ((((size_t)(b * 8 + hh) * 64 + (m >> 5)) * 4 + (d >> 4)) * 64
                       + ((d >> 3) & 1) * 32 + (m & 31)) * 8 + (d & 7);
        Kp[addr] = f2bf(ak[rt][ct][r]);
      }
      int m = r0g & 2047;
      size_t addr = ((((size_t)(b * 8 + hh) * 64 + (m >> 5)) * 4
                      + ((m >> 4) & 1) * 2 + (d >> 5)) * 64
                     + ((m >> 3) & 1) * 32 + (d & 31)) * 8 + (m & 7);
      ushort4 o;
      o.x = f2bf(av[rt][ct][0]); o.y = f2bf(av[rt][ct][1]);
      o.z = f2bf(av[rt][ct][2]); o.w = f2bf(av[rt][ct][3]);
      *(ushort4*)(Vp + addr) = o;
    }
  }
}

// ---------------- flash attention: NJS=1, 2-tile ILP, lsum via MFMA -----------
// qb pre-scaled by 0.125*log2(e). Kp/Vp fragment-packed. Each block owns all
// 2048 keys for its 128 q-rows -> final bf16 out, no partials/combine.
// Softmax denominator computed ON THE MFMA PIPE: Lacc = mfma(ones, P, Lacc)
// (rows identical = key-sum per query) -- removes 64 VALU adds/group and makes
// numerator & denominator share the same bf16 P (truncation bias cancels).
__global__ __launch_bounds__(256, 2) void attn_kernel(
    const u16* __restrict__ qb, const u16* __restrict__ Kp,
    const u16* __restrict__ Vp, u16* __restrict__ ob) {
  const int lane = threadIdx.x & 63, wave = threadIdx.x >> 6;
  const int l32 = lane & 31;
  const int hi = lane >> 5;           // half-wave index
  const int bid = blockIdx.x;
  const int bh = bid & 31;            // low bits -> XCD locality
  const int qblk = bid >> 5;          // 0..15
  const int b = bh >> 3, h = bh & 7;
  const int q0 = (qblk * 4 + wave) * 32;
  const int rowg = b * 2048 + q0 + l32;

  __shared__ __align__(16) u16 sK[2][2][2048], sV[2][2][2048];   // [buf][tile][..]

  const u16* qp = qb + (size_t)rowg * 512 + h * 64 + hi * 8;
  frag16 qf0 = *(const frag16*)(qp);
  frag16 qf1 = *(const frag16*)(qp + 16);
  frag16 qf2 = *(const frag16*)(qp + 32);
  frag16 qf3 = *(const frag16*)(qp + 48);

  frag16 ones;
  #pragma unroll
  for (int i = 0; i < 8; ++i) ones[i] = (short)0x3F80;   // bf16 1.0

  facc16 O0 = {}, O1 = {}, Lacc = {};

  const size_t ts = 2048;  // u16 per 32-key tile
  const u16* kpb = Kp + (size_t)(bh * 64) * ts + wave * 512 + lane * 8;
  const u16* vpb = Vp + (size_t)(bh * 64) * ts + wave * 512 + lane * 8;

  // preload group 0 (tiles 0,1) into buffer 0
  gld16(kpb,      sK[0][0] + wave * 512);
  gld16(kpb + ts, sK[0][1] + wave * 512);
  gld16(vpb,      sV[0][0] + wave * 512);
  gld16(vpb + ts, sV[0][1] + wave * 512);

  for (int g = 0; g < 32; ++g) {
    const int p = g & 1;
    __syncthreads();                    // drains buffer-p loads
    if (g + 1 < 32) {                   // prefetch next group
      const size_t t2 = (size_t)(2 * g + 2) * ts;
      gld16(kpb + t2,      sK[p ^ 1][0] + wave * 512);
      gld16(kpb + t2 + ts, sK[p ^ 1][1] + wave * 512);
      gld16(vpb + t2,      sV[p ^ 1][0] + wave * 512);
      gld16(vpb + t2 + ts, sV[p ^ 1][1] + wave * 512);
    }

    frag16 kfa[4], kfb[4];
    #pragma unroll
    for (int i = 0; i < 4; ++i) {
      kfa[i] = *(const frag16*)(sK[p][0] + i * 512 + lane * 8);
      kfb[i] = *(const frag16*)(sK[p][1] + i * 512 + lane * 8);
    }

    // two independent S chains (ILP x2)
    facc16 Sa = {}, Sb = {};
    Sa = __builtin_amdgcn_mfma_f32_32x32x16_bf16(kfa[0], qf0, Sa, 0, 0, 0);
    Sb = __builtin_amdgcn_mfma_f32_32x32x16_bf16(kfb[0], qf0, Sb, 0, 0, 0);
    Sa = __builtin_amdgcn_mfma_f32_32x32x16_bf16(kfa[1], qf1, Sa, 0, 0, 0);
    Sb = __builtin_amdgcn_mfma_f32_32x32x16_bf16(kfb[1], qf1, Sb, 0, 0, 0);
    Sa = __builtin_amdgcn_mfma_f32_32x32x16_bf16(kfa[2], qf2, Sa, 0, 0, 0);
    Sb = __builtin_amdgcn_mfma_f32_32x32x16_bf16(kfb[2], qf2, Sb, 0, 0, 0);
    Sa = __builtin_amdgcn_mfma_f32_32x32x16_bf16(kfa[3], qf3, Sa, 0, 0, 0);
    Sb = __builtin_amdgcn_mfma_f32_32x32x16_bf16(kfb[3], qf3, Sb, 0, 0, 0);

    float ea[16], eb[16];
    #pragma unroll
    for (int r = 0; r < 16; ++r) { ea[r] = __builtin_amdgcn_exp2f(Sa[r]);
                                   eb[r] = __builtin_amdgcn_exp2f(Sb[r]); }

    // S^T C-layout -> P B-operand: truncating pack, half-wave dword swap.
    unsigned pua[2][4], pub[2][4];
    #pragma unroll
    for (int c = 0; c < 2; ++c) {
      {
        const float* ee = ea + c * 8;
        unsigned L0 = pkbf_t(ee[0], ee[1]);
        unsigned L1 = pkbf_t(ee[2], ee[3]);
        unsigned H0 = pkbf_t(ee[4], ee[5]);
        unsigned H1 = pkbf_t(ee[6], ee[7]);
        unsigned Y0 = hi ? L0 : H0;
        unsigned Y1 = hi ? L1 : H1;
        unsigned X0 = (unsigned)__shfl_xor((int)Y0, 32);
        unsigned X1 = (unsigned)__shfl_xor((int)Y1, 32);
        pua[c][0] = hi ? X0 : L0;
        pua[c][1] = hi ? X1 : L1;
        pua[c][2] = hi ? H0 : X0;
        pua[c][3] = hi ? H1 : X1;
      }
      {
        const float* ee = eb + c * 8;
        unsigned L0 = pkbf_t(ee[0], ee[1]);
        unsigned L1 = pkbf_t(ee[2], ee[3]);
        unsigned H0 = pkbf_t(ee[4], ee[5]);
        unsigned H1 = pkbf_t(ee[6], ee[7]);
        unsigned Y0 = hi ? L0 : H0;
        unsigned Y1 = hi ? L1 : H1;
        unsigned X0 = (unsigned)__shfl_xor((int)Y0, 32);
        unsigned X1 = (unsigned)__shfl_xor((int)Y1, 32);
        pub[c][0] = hi ? X0 : L0;
        pub[c][1] = hi ? X1 : L1;
        pub[c][2] = hi ? H0 : X0;
        pub[c][3] = hi ? H1 : X1;
      }
    }
    frag16 Pa0 = *(frag16*)&pua[0][0];
    frag16 Pa1 = *(frag16*)&pua[1][0];
    frag16 Pb0 = *(frag16*)&pub[0][0];
    frag16 Pb1 = *(frag16*)&pub[1][0];

    // denominator on the MFMA pipe
    Lacc = __builtin_amdgcn_mfma_f32_32x32x16_bf16(ones, Pa0, Lacc, 0, 0, 0);
    Lacc = __builtin_amdgcn_mfma_f32_32x32x16_bf16(ones, Pa1, Lacc, 0, 0, 0);
    Lacc = __builtin_amdgcn_mfma_f32_32x32x16_bf16(ones, Pb0, Lacc, 0, 0, 0);
    Lacc = __builtin_amdgcn_mfma_f32_32x32x16_bf16(ones, Pb1, Lacc, 0, 0, 0);

    frag16 vfa[4], vfb[4];
    #pragma unroll
    for (int i = 0; i < 4; ++i) {
      vfa[i] = *(const frag16*)(sV[p][0] + i * 512 + lane * 8);
      vfb[i] = *(const frag16*)(sV[p][1] + i * 512 + lane * 8);
    }

    O0 = __builtin_amdgcn_mfma_f32_32x32x16_bf16(vfa[0], Pa0, O0, 0, 0, 0);
    O1 = __builtin_amdgcn_mfma_f32_32x32x16_bf16(vfa[1], Pa0, O1, 0, 0, 0);
    O0 = __builtin_amdgcn_mfma_f32_32x32x16_bf16(vfa[2], Pa1, O0, 0, 0, 0);
    O1 = __builtin_amdgcn_mfma_f32_32x32x16_bf16(vfa[3], Pa1, O1, 0, 0, 0);
    O0 = __builtin_amdgcn_mfma_f32_32x32x16_bf16(vfb[0], Pb0, O0, 0, 0, 0);
    O1 = __builtin_amdgcn_mfma_f32_32x32x16_bf16(vfb[1], Pb0, O1, 0, 0, 0);
    O0 = __builtin_amdgcn_mfma_f32_32x32x16_bf16(vfb[2], Pb1, O0, 0, 0, 0);
    O1 = __builtin_amdgcn_mfma_f32_32x32x16_bf16(vfb[3], Pb1, O1, 0, 0, 0);
  }

  // every row of Lacc equals the key-sum for query q = l32
  float rinv = 1.0f / Lacc[0];

  // O^T C-layout: col=q=l32, row=d = dt*32 + 8*rq + 4*hi + (reg&3). Final bf16.
  u16* op = ob + (size_t)rowg * 512 + h * 64;
  #pragma unroll
  for (int dt = 0; dt < 2; ++dt) {
    #pragma unroll
    for (int rq = 0; rq < 4; ++rq) {
      float v0, v1, v2, v3;
      if (dt == 0) { v0 = O0[rq*4]; v1 = O0[rq*4+1]; v2 = O0[rq*4+2]; v3 = O0[rq*4+3]; }
      else         { v0 = O1[rq*4]; v1 = O1[rq*4+1]; v2 = O1[rq*4+2]; v3 = O1[rq*4+3]; }
      uint2 pk;
      pk.x = pkbf(v0 * rinv, v1 * rinv);
      pk.y = pkbf(v2 * rinv, v3 * rinv);
      int d0 = dt * 32 + 8 * rq + 4 * hi;
      *(uint2*)(op + d0) = pk;
    }
  }
}

// ---------------- out-projection GEMM ----------------------------------------
__global__ __launch_bounds__(256) void gemm_out(const u16* __restrict__ A,
    const u16* __restrict__ BT, float* __restrict__ C,
    const float* __restrict__ bias) {
  __shared__ __align__(16) u16 As0[128 * 32], As1[128 * 32];
  __shared__ __align__(16) u16 Bs0[64 * 32], Bs1[64 * 32];
  int n0 = (blockIdx.x & 7) * 64, m0 = (blockIdx.x >> 3) * 128;
  gemm128_body<2>(A, BT, C, bias, m0, n0, 1.f, As0, As1, Bs0, Bs1);
}

// ---------------- launch ------------------------------------------------------
extern "C" void kernel_launch(void* const* d_in, const int* in_sizes, int n_in,
                              void* d_out, int out_size, void* d_ws, size_t ws_size,
                              hipStream_t stream) {
  const float* x   = (const float*)d_in[0];
  const float* ctx = (const float*)d_in[1];
  const float* Wq  = (const float*)d_in[2];
  const float* Wk  = (const float*)d_in[3];
  const float* Wv  = (const float*)d_in[4];
  const float* W1  = (const float*)d_in[5];
  const float* b1  = (const float*)d_in[6];
  const float* W2  = (const float*)d_in[7];
  const float* b2  = (const float*)d_in[8];
  const float* Wo  = (const float*)d_in[9];
  const float* bo  = (const float*)d_in[10];
  float* out = (float*)d_out;

  char* ws = (char*)d_ws;
  size_t off = 0;
  auto alloc = [&](size_t bytes) {
    char* p = ws + off;
    off += (bytes + 255) & ~(size_t)255;
    return p;
  };
  u16* xb    = (u16*)alloc(8192ull * 512 * 2);
  u16* qb    = (u16*)alloc(8192ull * 512 * 2);
  u16* Kp    = (u16*)alloc(8192ull * 512 * 2);
  u16* Vp    = (u16*)alloc(8192ull * 512 * 2);
  u16* ob    = (u16*)alloc(8192ull * 512 * 2);
  u16* gctx  = (u16*)alloc(8192ull * 64 * 2);
  u16* WqT   = (u16*)alloc(512ull * 512 * 2);
  u16* WkT   = (u16*)alloc(512ull * 64 * 2);
  u16* WvT   = (u16*)alloc(512ull * 64 * 2);
  u16* WoT   = (u16*)alloc(512ull * 512 * 2);

  prep_gate_kernel<<<6288, 256, 0, stream>>>((const float4*)x, Wq, Wk, Wv, Wo,
                                             ctx, W1, b1, W2, b2,
                                             xb, WqT, WkT, WvT, WoT, gctx);
  proj_kernel<<<1536, 256, 0, stream>>>(xb, WqT, qb, gctx, WkT, WvT, Kp, Vp);
  attn_kernel<<<512, 256, 0, stream>>>(qb, Kp, Vp, ob);
  gemm_out<<<512, 256, 0, stream>>>(ob, WoT, out, bo);
}